// Round 10
// baseline (208.459 us; speedup 1.0000x reference)
//
#include <hip/hip_runtime.h>

#define S_LEN  2048
#define DMODEL 1024
#define NHEAD  16
#define DKDIM  64
#define NBATCH 2

typedef short bf16x8 __attribute__((ext_vector_type(8)));
typedef float f32x4  __attribute__((ext_vector_type(4)));
typedef float f32x16 __attribute__((ext_vector_type(16)));

__device__ __forceinline__ unsigned short f2b(float f){
  unsigned int x = __float_as_uint(f);
  return (unsigned short)((x + 0x7FFFu + ((x >> 16) & 1u)) >> 16);  // RNE
}
__device__ __forceinline__ bf16x8 ld8(const unsigned short* p){
  return *reinterpret_cast<const bf16x8*>(p);
}
// async global->LDS DMA, 16B per lane; lds base must be wave-uniform (HW adds lane*16)
__device__ __forceinline__ void gld16(const unsigned short* g, unsigned short* l){
  __builtin_amdgcn_global_load_lds(
      (const __attribute__((address_space(1))) unsigned int*)(uintptr_t)g,
      (__attribute__((address_space(3))) unsigned int*)(uintptr_t)l,
      16, 0, 0);
}
__device__ __forceinline__ float fexp2(float x){
#if __has_builtin(__builtin_amdgcn_exp2f)
  return __builtin_amdgcn_exp2f(x);
#else
  return exp2f(x);
#endif
}
// v_permlane32_swap_b32: exchanges lane-halves between two regs
__device__ __forceinline__ void pl32swap(unsigned int &a, unsigned int &b){
  asm("v_permlane32_swap_b32 %0, %1" : "+v"(a), "+v"(b));
}

// ------- fused prep: z<4 -> weight transpose+convert; z==4 -> X f32->bf16 convert -------
__global__ __launch_bounds__(256) void prep(
    const float* __restrict__ X, unsigned short* __restrict__ Xc,
    const float* __restrict__ W0, const float* __restrict__ W1,
    const float* __restrict__ W2, const float* __restrict__ W3,
    unsigned short* __restrict__ Wt)
{
  if(blockIdx.z == 4){
    // convert slice: 256 blocks (bx,by in 16x16), 8 chunks of 2048 floats each
    const int bid = blockIdx.y * 16 + blockIdx.x;
    #pragma unroll
    for(int it=0; it<8; it++){
      const size_t i0 = (((size_t)bid*8 + it)*2048) + threadIdx.x*8;
      const float4 a = *reinterpret_cast<const float4*>(X + i0);
      const float4 b = *reinterpret_cast<const float4*>(X + i0 + 4);
      bf16x8 o;
      o[0]=(short)f2b(a.x); o[1]=(short)f2b(a.y); o[2]=(short)f2b(a.z); o[3]=(short)f2b(a.w);
      o[4]=(short)f2b(b.x); o[5]=(short)f2b(b.y); o[6]=(short)f2b(b.z); o[7]=(short)f2b(b.w);
      *reinterpret_cast<bf16x8*>(Xc + i0) = o;
    }
    return;
  }
  __shared__ unsigned short tile[64][65];
  const float* src = (blockIdx.z==0)?W0:(blockIdx.z==1)?W1:(blockIdx.z==2)?W2:W3;
  unsigned short* dst = Wt + (size_t)blockIdx.z * DMODEL * DMODEL;
  const int r0 = blockIdx.x * 64, c0 = blockIdx.y * 64;
  #pragma unroll
  for(int t=0;t<16;t++){
    int idx = threadIdx.x + t*256;
    int r = idx >> 6, c = idx & 63;
    tile[r][c] = f2b(src[(size_t)(r0+r)*DMODEL + (c0+c)]);
  }
  __syncthreads();
  #pragma unroll
  for(int t=0;t<16;t++){
    int idx = threadIdx.x + t*256;
    int r = idx >> 6, c = idx & 63;
    dst[(size_t)(c0+r)*DMODEL + (r0+c)] = tile[c][r];
  }
}

// ---------------- QKV projection GEMM: 128x128 tile, BK=32, DOUBLE-BUFFERED staging ----
// T3 minimum-2-phase: STAGE(next) issued BEFORE compute(cur); ONE barrier per k-step.
// z=0 -> q (PRE-SCALED by 0.125*log2(e)); z=1 -> k; z=2 -> vT via transposed GEMM.
__global__ __launch_bounds__(256) void gemm_qkv(
    const unsigned short* __restrict__ Xc,
    const unsigned short* __restrict__ WtBase,
    const float* __restrict__ bq,
    const float* __restrict__ bk,
    const float* __restrict__ bv,
    unsigned short* __restrict__ q_ws,
    unsigned short* __restrict__ k_ws,
    unsigned short* __restrict__ vT_ws)
{
  __shared__ __align__(16) unsigned short sA[2][128][32];
  __shared__ __align__(16) unsigned short sB[2][128][32];
  const int z = blockIdx.z;
  const float* bias = (z==0) ? bq : ((z==1) ? bk : bv);
  const float scl = (z==0) ? 0.18033688011f : 1.0f;   // 0.125 * log2(e)
  const unsigned short* Ap; const unsigned short* Bp; int m0, n0;
  if(z == 2){ Ap = WtBase + 2*(size_t)DMODEL*DMODEL; Bp = Xc;
              m0 = blockIdx.y * 128; n0 = blockIdx.x * 128; }
  else      { Ap = Xc; Bp = WtBase + (size_t)z*DMODEL*DMODEL;
              m0 = blockIdx.x * 128; n0 = blockIdx.y * 128; }
  const int tid = threadIdx.x;
  const int w = tid >> 6, lane = tid & 63, quad = lane >> 4, lm = lane & 15;
  const int wm = (w & 1) * 64, wn = (w >> 1) * 64;
  const int srow = lane >> 2, scol = (lane & 3) * 8;   // staging lane coords

  f32x4 acc[4][4];
  #pragma unroll
  for(int i=0;i<4;i++)
    #pragma unroll
    for(int j=0;j<4;j++){ f32x4 z4 = {0.f,0.f,0.f,0.f}; acc[i][j] = z4; }

  // prologue: stage k0=0 into buf 0
  #pragma unroll
  for(int j=0;j<2;j++){
    gld16(Ap + (size_t)(m0 + w*32 + j*16 + srow)*DMODEL + scol, &sA[0][w*32 + j*16][0]);
    gld16(Bp + (size_t)(n0 + w*32 + j*16 + srow)*DMODEL + scol, &sB[0][w*32 + j*16][0]);
  }
  __syncthreads();

  int cur = 0;
  for(int k0=0;k0<DMODEL;k0+=32){
    if(k0 + 32 < DMODEL){
      #pragma unroll
      for(int j=0;j<2;j++){
        gld16(Ap + (size_t)(m0 + w*32 + j*16 + srow)*DMODEL + k0+32 + scol, &sA[cur^1][w*32 + j*16][0]);
        gld16(Bp + (size_t)(n0 + w*32 + j*16 + srow)*DMODEL + k0+32 + scol, &sB[cur^1][w*32 + j*16][0]);
      }
    }
    bf16x8 a[4], b[4];
    #pragma unroll
    for(int i=0;i<4;i++) a[i] = ld8(&sA[cur][wm + i*16 + lm][quad*8]);
    #pragma unroll
    for(int j=0;j<4;j++) b[j] = ld8(&sB[cur][wn + j*16 + lm][quad*8]);
    #pragma unroll
    for(int i=0;i<4;i++)
      #pragma unroll
      for(int j=0;j<4;j++)
        acc[i][j] = __builtin_amdgcn_mfma_f32_16x16x32_bf16(a[i], b[j], acc[i][j], 0, 0, 0);
    __syncthreads();       // drains this step's STAGE(next) vmcnt AFTER compute
    cur ^= 1;
  }

  if(z == 2){
    // C/D: row (A-side) = d-coord, col (B-side) = s-coord; bias indexed by row
    #pragma unroll
    for(int i=0;i<4;i++){
      #pragma unroll
      for(int r=0;r<4;r++){
        const int row = m0 + wm + i*16 + quad*4 + r;    // 0..1023: h,d
        const int h_ = row >> 6, d_ = row & 63;
        const float bb = bias[row];
        #pragma unroll
        for(int j=0;j<4;j++){
          const int c = n0 + wn + j*16 + lm;            // 0..4095: b,s (lm -> consecutive)
          const int b_ = c >> 11, s_ = c & 2047;
          vT_ws[((size_t)(b_*NHEAD + h_)*DKDIM + d_)*S_LEN + s_] = f2b(acc[i][j][r] + bb);
        }
      }
    }
  }else{
    #pragma unroll
    for(int j=0;j<4;j++){
      const int n  = n0 + wn + j*16 + lm;
      const float bb = bias[n] * scl;
      const int h_ = n >> 6, d_ = n & 63;
      #pragma unroll
      for(int i=0;i<4;i++){
        #pragma unroll
        for(int r=0;r<4;r++){
          const int m  = m0 + wm + i*16 + quad*4 + r;   // C/D: row = quad*4+reg
          const int b_ = m >> 11, s_ = m & 2047;
          const unsigned short o = f2b(fmaf(acc[i][j][r], scl, bb));
          if(z == 0) q_ws[((size_t)(b_*NHEAD + h_)*S_LEN + s_)*DKDIM + d_] = o;
          else       k_ws[((size_t)(b_*NHEAD + h_)*S_LEN + s_)*DKDIM + d_] = o;
        }
      }
    }
  }
}

// ---------------- flash attention v11: v10 + T5 setprio around MFMA clusters ----------
// Compute/math byte-identical to R8/R9's passing kernel; setprio is scheduler-only.
__global__ __launch_bounds__(128) void flash_attn(
    const unsigned short* __restrict__ q_ws,
    const unsigned short* __restrict__ k_ws,
    const unsigned short* __restrict__ vT_ws,
    unsigned short* __restrict__ attn_c)
{
  __shared__ __align__(16) unsigned short kt[2][64][64];   // [buf][j][k], chunk-swizzled
  __shared__ __align__(16) unsigned short vt[2][64][64];   // [buf][d][j], chunk-swizzled
  const int bh = blockIdx.x;
  const int b_ = bh >> 4, h_ = bh & 15;
  const int tid = threadIdx.x;
  const int w = tid >> 6, lane = tid & 63;
  const int l = lane & 31, hi = lane >> 5;
  const int r0 = blockIdx.y * 64 + w * 32;

  const unsigned short* qp = q_ws  + ((size_t)bh * S_LEN + r0) * DKDIM;
  const unsigned short* kp = k_ws  + (size_t)bh * S_LEN * DKDIM;
  const unsigned short* vp = vT_ws + (size_t)bh * DKDIM * S_LEN;

  bf16x8 qf[4];
  #pragma unroll
  for(int m=0;m<4;m++)
    qf[m] = ld8(qp + (size_t)l*DKDIM + m*16 + hi*8);

  f32x16 o_acc[2];
  #pragma unroll
  for(int i=0;i<16;i++){ o_acc[0][i] = 0.f; o_acc[1][i] = 0.f; }
  float rsum = 0.f;

  const int srow = (lane >> 3) & 7;          // row within 8-row group
  const int schk = (lane & 7) ^ srow;        // pre-swizzled global 16B-chunk index
  int kofs[4], vofs[4];                      // per-lane global offsets (shorts)
  #pragma unroll
  for(int p=0;p<4;p++){
    const int row = w*32 + p*8 + srow;       // row&7 == srow
    kofs[p] = row*DKDIM + schk*8;            // + t*4096 per tile
    vofs[p] = row*S_LEN + schk*8;            // + t*64 per tile
  }

  #pragma unroll
  for(int p=0;p<4;p++){
    gld16(kp + kofs[p], &kt[0][w*32 + p*8][0]);
    gld16(vp + vofs[p], &vt[0][w*32 + p*8][0]);
  }
  __syncthreads();

  for(int t=0;t<32;t++){
    const int buf = t & 1, nb = buf ^ 1;
    if(t < 31){
      #pragma unroll
      for(int p=0;p<4;p++){
        gld16(kp + (t+1)*4096 + kofs[p], &kt[nb][w*32 + p*8][0]);
        gld16(vp + (t+1)*64   + vofs[p], &vt[nb][w*32 + p*8][0]);
      }
    }

    // ---- QK^T for BOTH j-blocks ----
    f32x16 sacc0, sacc1;
    #pragma unroll
    for(int q=0;q<16;q++){ sacc0[q] = 0.f; sacc1[q] = 0.f; }
    __builtin_amdgcn_s_setprio(1);
    #pragma unroll
    for(int m=0;m<4;m++){
      bf16x8 kf0 = ld8(&kt[buf][     l][((2*m + hi) ^ (l & 7)) * 8]);
      bf16x8 kf1 = ld8(&kt[buf][32 + l][((2*m + hi) ^ (l & 7)) * 8]);
      sacc0 = __builtin_amdgcn_mfma_f32_32x32x16_bf16(kf0, qf[m], sacc0, 0, 0, 0);
      sacc1 = __builtin_amdgcn_mfma_f32_32x32x16_bf16(kf1, qf[m], sacc1, 0, 0, 0);
    }
    __builtin_amdgcn_s_setprio(0);

    // ---- softmax jb=0 ----
    unsigned int pk0[8];
    {
      float ea = 0.f;
      #pragma unroll
      for(int r2=0;r2<4;r2++){
        const float e0 = fexp2(sacc0[4*r2+0]);
        const float e1 = fexp2(sacc0[4*r2+1]);
        const float e2 = fexp2(sacc0[4*r2+2]);
        const float e3 = fexp2(sacc0[4*r2+3]);
        ea += (e0+e1)+(e2+e3);
        const unsigned int u0 = __float_as_uint(e0) + 0x8000u;
        const unsigned int u1 = __float_as_uint(e1) + 0x8000u;
        const unsigned int u2 = __float_as_uint(e2) + 0x8000u;
        const unsigned int u3 = __float_as_uint(e3) + 0x8000u;
        pk0[2*r2]   = __builtin_amdgcn_perm(u1, u0, 0x07060302u);
        pk0[2*r2+1] = __builtin_amdgcn_perm(u3, u2, 0x07060302u);
      }
      rsum += ea;
    }

    // ---- PV jb=0 ----
    __builtin_amdgcn_s_setprio(1);
    #pragma unroll
    for(int c=0;c<2;c++){
      unsigned int a0 = pk0[4*c],   b0 = pk0[4*c+2];
      unsigned int a1 = pk0[4*c+1], b1 = pk0[4*c+3];
      pl32swap(a0, b0);
      pl32swap(a1, b1);
      union { unsigned int u[4]; bf16x8 v; } pa;
      pa.u[0] = a0; pa.u[1] = a1; pa.u[2] = b0; pa.u[3] = b1;
      #pragma unroll
      for(int dblk=0;dblk<2;dblk++){
        bf16x8 vf = ld8(&vt[buf][dblk*32 + l][((2*c + hi) ^ (l & 7)) * 8]);
        o_acc[dblk] = __builtin_amdgcn_mfma_f32_32x32x16_bf16(pa.v, vf, o_acc[dblk], 0, 0, 0);
      }
    }
    __builtin_amdgcn_s_setprio(0);

    // ---- softmax jb=1 ----
    unsigned int pk1[8];
    {
      float ea = 0.f;
      #pragma unroll
      for(int r2=0;r2<4;r2++){
        const float e0 = fexp2(sacc1[4*r2+0]);
        const float e1 = fexp2(sacc1[4*r2+1]);
        const float e2 = fexp2(sacc1[4*r2+2]);
        const float e3 = fexp2(sacc1[4*r2+3]);
        ea += (e0+e1)+(e2+e3);
        const unsigned int u0 = __float_as_uint(e0) + 0x8000u;
        const unsigned int u1 = __float_as_uint(e1) + 0x8000u;
        const unsigned int u2 = __float_as_uint(e2) + 0x8000u;
        const unsigned int u3 = __float_as_uint(e3) + 0x8000u;
        pk1[2*r2]   = __builtin_amdgcn_perm(u1, u0, 0x07060302u);
        pk1[2*r2+1] = __builtin_amdgcn_perm(u3, u2, 0x07060302u);
      }
      rsum += ea;
    }

    // ---- PV jb=1 ----
    __builtin_amdgcn_s_setprio(1);
    #pragma unroll
    for(int c=0;c<2;c++){
      unsigned int a0 = pk1[4*c],   b0 = pk1[4*c+2];
      unsigned int a1 = pk1[4*c+1], b1 = pk1[4*c+3];
      pl32swap(a0, b0);
      pl32swap(a1, b1);
      union { unsigned int u[4]; bf16x8 v; } pa;
      pa.u[0] = a0; pa.u[1] = a1; pa.u[2] = b0; pa.u[3] = b1;
      #pragma unroll
      for(int dblk=0;dblk<2;dblk++){
        bf16x8 vf = ld8(&vt[buf][dblk*32 + l][((4 + 2*c + hi) ^ (l & 7)) * 8]);
        o_acc[dblk] = __builtin_amdgcn_mfma_f32_32x32x16_bf16(pa.v, vf, o_acc[dblk], 0, 0, 0);
      }
    }
    __builtin_amdgcn_s_setprio(0);

    __syncthreads();
  }

  rsum += __shfl_xor(rsum, 32);
  const float rinv_l = __frcp_rn(rsum);

  #pragma unroll
  for(int r=0;r<16;r++){
    const int qr = (r&3) + 8*(r>>2) + 4*hi;
    const float ri = __shfl(rinv_l, qr);
    const size_t ob = ((size_t)(b_*S_LEN + r0 + qr))*DMODEL + h_*DKDIM + l;
    attn_c[ob]      = f2b(o_acc[0][r] * ri);
    attn_c[ob + 32] = f2b(o_acc[1][r] * ri);
  }
}

// ---------------- output projection: 128x128, DOUBLE-BUFFERED (T3 2-phase) ----------
__global__ __launch_bounds__(256) void gemm_out(
    const unsigned short* __restrict__ A,
    const unsigned short* __restrict__ Wt,
    const float* __restrict__ bias,
    float* __restrict__ out)
{
  __shared__ __align__(16) unsigned short sA[2][128][32];
  __shared__ __align__(16) unsigned short sB[2][128][32];
  const int m0 = blockIdx.x * 128, n0 = blockIdx.y * 128;
  const int tid = threadIdx.x;
  const int w = tid >> 6, lane = tid & 63, quad = lane >> 4, lm = lane & 15;
  const int wm = (w & 1) * 64, wn = (w >> 1) * 64;
  const int srow = lane >> 2, scol = (lane & 3) * 8;

  f32x4 acc[4][4];
  #pragma unroll
  for(int i=0;i<4;i++)
    #pragma unroll
    for(int j=0;j<4;j++){ f32x4 z4 = {0.f,0.f,0.f,0.f}; acc[i][j] = z4; }

  #pragma unroll
  for(int j=0;j<2;j++){
    gld16(A  + (size_t)(m0 + w*32 + j*16 + srow)*DMODEL + scol, &sA[0][w*32 + j*16][0]);
    gld16(Wt + (size_t)(n0 + w*32 + j*16 + srow)*DMODEL + scol, &sB[0][w*32 + j*16][0]);
  }
  __syncthreads();

  int cur = 0;
  for(int k0=0;k0<DMODEL;k0+=32){
    if(k0 + 32 < DMODEL){
      #pragma unroll
      for(int j=0;j<2;j++){
        gld16(A  + (size_t)(m0 + w*32 + j*16 + srow)*DMODEL + k0+32 + scol, &sA[cur^1][w*32 + j*16][0]);
        gld16(Wt + (size_t)(n0 + w*32 + j*16 + srow)*DMODEL + k0+32 + scol, &sB[cur^1][w*32 + j*16][0]);
      }
    }
    bf16x8 a[4], b[4];
    #pragma unroll
    for(int i=0;i<4;i++) a[i] = ld8(&sA[cur][wm + i*16 + lm][quad*8]);
    #pragma unroll
    for(int j=0;j<4;j++) b[j] = ld8(&sB[cur][wn + j*16 + lm][quad*8]);
    #pragma unroll
    for(int i=0;i<4;i++)
      #pragma unroll
      for(int j=0;j<4;j++)
        acc[i][j] = __builtin_amdgcn_mfma_f32_16x16x32_bf16(a[i], b[j], acc[i][j], 0, 0, 0);
    __syncthreads();
    cur ^= 1;
  }

  #pragma unroll
  for(int j=0;j<4;j++){
    const int n = n0 + wn + j*16 + lm;
    const float bb = bias[n];
    #pragma unroll
    for(int i=0;i<4;i++){
      #pragma unroll
      for(int r=0;r<4;r++){
        const int m = m0 + wm + i*16 + quad*4 + r;
        out[(size_t)m*DMODEL + n] = acc[i][j][r] + bb;
      }
    }
  }
}

extern "C" void kernel_launch(void* const* d_in, const int* in_sizes, int n_in,
                              void* d_out, int out_size, void* d_ws, size_t ws_size,
                              hipStream_t stream)
{
  const float* X  = (const float*)d_in[0];
  const float* Wq = (const float*)d_in[1];
  const float* bq = (const float*)d_in[2];
  const float* Wk = (const float*)d_in[3];
  const float* bk = (const float*)d_in[4];
  const float* Wv = (const float*)d_in[5];
  const float* bv = (const float*)d_in[6];
  const float* Wo = (const float*)d_in[7];
  const float* bo = (const float*)d_in[8];

  unsigned short* ws = (unsigned short*)d_ws;
  const size_t WMAT = (size_t)DMODEL * DMODEL;                 // 1M elems
  const size_t QKV  = (size_t)NBATCH * NHEAD * S_LEN * DKDIM;  // 4M elems
  unsigned short* Wt     = ws;               // 4 transposed bf16 weights (4M elems)
  unsigned short* Xc     = ws + 4*WMAT;      // bf16 X (4M elems)
  unsigned short* q_ws   = Xc + QKV;
  unsigned short* k_ws   = q_ws + QKV;
  unsigned short* vT_ws  = k_ws + QKV;
  unsigned short* attn_c = Xc;               // alias: Xc dead after gemm_qkv
  float* out = (float*)d_out;

  prep       <<<dim3(16,16,5),  256, 0, stream>>>(X, Xc, Wq, Wk, Wv, Wo, Wt);
  gemm_qkv   <<<dim3(32,8,3),   256, 0, stream>>>(Xc, Wt, bq, bk, bv, q_ws, k_ws, vT_ws);
  flash_attn <<<dim3(32,32),    128, 0, stream>>>(q_ws, k_ws, vT_ws, attn_c);
  gemm_out   <<<dim3(32,8),     256, 0, stream>>>(attn_c, Wt + 3*WMAT, bo, out);
}

// Round 11
// 204.355 us; speedup vs baseline: 1.0201x; 1.0201x over previous
//
#include <hip/hip_runtime.h>

#define S_LEN  2048
#define DMODEL 1024
#define NHEAD  16
#define DKDIM  64
#define NBATCH 2

typedef short bf16x8 __attribute__((ext_vector_type(8)));
typedef float f32x4  __attribute__((ext_vector_type(4)));
typedef float f32x16 __attribute__((ext_vector_type(16)));

__device__ __forceinline__ unsigned short f2b(float f){
  unsigned int x = __float_as_uint(f);
  return (unsigned short)((x + 0x7FFFu + ((x >> 16) & 1u)) >> 16);  // RNE
}
__device__ __forceinline__ bf16x8 ld8(const unsigned short* p){
  return *reinterpret_cast<const bf16x8*>(p);
}
// async global->LDS DMA, 16B per lane; lds base must be wave-uniform (HW adds lane*16)
__device__ __forceinline__ void gld16(const unsigned short* g, unsigned short* l){
  __builtin_amdgcn_global_load_lds(
      (const __attribute__((address_space(1))) unsigned int*)(uintptr_t)g,
      (__attribute__((address_space(3))) unsigned int*)(uintptr_t)l,
      16, 0, 0);
}
__device__ __forceinline__ float fexp2(float x){
#if __has_builtin(__builtin_amdgcn_exp2f)
  return __builtin_amdgcn_exp2f(x);
#else
  return exp2f(x);
#endif
}
// v_permlane32_swap_b32: exchanges lane-halves between two regs
__device__ __forceinline__ void pl32swap(unsigned int &a, unsigned int &b){
  asm("v_permlane32_swap_b32 %0, %1" : "+v"(a), "+v"(b));
}

// ---------------- X f32 -> bf16 convert (R9 configuration, restored) ----------------
__global__ __launch_bounds__(256) void convert_x(
    const float* __restrict__ X, unsigned short* __restrict__ Xc)
{
  const size_t i0 = ((size_t)blockIdx.x * 256 + threadIdx.x) * 8;
  const float4 a = *reinterpret_cast<const float4*>(X + i0);
  const float4 b = *reinterpret_cast<const float4*>(X + i0 + 4);
  bf16x8 o;
  o[0]=(short)f2b(a.x); o[1]=(short)f2b(a.y); o[2]=(short)f2b(a.z); o[3]=(short)f2b(a.w);
  o[4]=(short)f2b(b.x); o[5]=(short)f2b(b.y); o[6]=(short)f2b(b.z); o[7]=(short)f2b(b.w);
  *reinterpret_cast<bf16x8*>(Xc + i0) = o;
}

// ---------------- weight transpose+convert: Wt[n*1024+k] = bf16(W[k*1024+n]) ----------------
__global__ __launch_bounds__(256) void transpose_w(
    const float* __restrict__ W0, const float* __restrict__ W1,
    const float* __restrict__ W2, const float* __restrict__ W3,
    unsigned short* __restrict__ Wt)
{
  __shared__ unsigned short tile[64][65];
  const float* src = (blockIdx.z==0)?W0:(blockIdx.z==1)?W1:(blockIdx.z==2)?W2:W3;
  unsigned short* dst = Wt + (size_t)blockIdx.z * DMODEL * DMODEL;
  const int r0 = blockIdx.x * 64, c0 = blockIdx.y * 64;
  #pragma unroll
  for(int t=0;t<16;t++){
    int idx = threadIdx.x + t*256;
    int r = idx >> 6, c = idx & 63;
    tile[r][c] = f2b(src[(size_t)(r0+r)*DMODEL + (c0+c)]);
  }
  __syncthreads();
  #pragma unroll
  for(int t=0;t<16;t++){
    int idx = threadIdx.x + t*256;
    int r = idx >> 6, c = idx & 63;
    dst[(size_t)(c0+r)*DMODEL + (r0+c)] = tile[c][r];
  }
}

// ---------------- QKV projection GEMM: 128x128 tile, BK=32, DOUBLE-BUFFERED staging ----
// T3 minimum-2-phase: STAGE(next) issued BEFORE compute(cur); ONE barrier per k-step.
// z=0 -> q (PRE-SCALED by 0.125*log2(e)); z=1 -> k; z=2 -> vT via transposed GEMM.
__global__ __launch_bounds__(256) void gemm_qkv(
    const unsigned short* __restrict__ Xc,
    const unsigned short* __restrict__ WtBase,
    const float* __restrict__ bq,
    const float* __restrict__ bk,
    const float* __restrict__ bv,
    unsigned short* __restrict__ q_ws,
    unsigned short* __restrict__ k_ws,
    unsigned short* __restrict__ vT_ws)
{
  __shared__ __align__(16) unsigned short sA[2][128][32];
  __shared__ __align__(16) unsigned short sB[2][128][32];
  const int z = blockIdx.z;
  const float* bias = (z==0) ? bq : ((z==1) ? bk : bv);
  const float scl = (z==0) ? 0.18033688011f : 1.0f;   // 0.125 * log2(e)
  const unsigned short* Ap; const unsigned short* Bp; int m0, n0;
  if(z == 2){ Ap = WtBase + 2*(size_t)DMODEL*DMODEL; Bp = Xc;
              m0 = blockIdx.y * 128; n0 = blockIdx.x * 128; }
  else      { Ap = Xc; Bp = WtBase + (size_t)z*DMODEL*DMODEL;
              m0 = blockIdx.x * 128; n0 = blockIdx.y * 128; }
  const int tid = threadIdx.x;
  const int w = tid >> 6, lane = tid & 63, quad = lane >> 4, lm = lane & 15;
  const int wm = (w & 1) * 64, wn = (w >> 1) * 64;
  const int srow = lane >> 2, scol = (lane & 3) * 8;   // staging lane coords

  f32x4 acc[4][4];
  #pragma unroll
  for(int i=0;i<4;i++)
    #pragma unroll
    for(int j=0;j<4;j++){ f32x4 z4 = {0.f,0.f,0.f,0.f}; acc[i][j] = z4; }

  // prologue: stage k0=0 into buf 0
  #pragma unroll
  for(int j=0;j<2;j++){
    gld16(Ap + (size_t)(m0 + w*32 + j*16 + srow)*DMODEL + scol, &sA[0][w*32 + j*16][0]);
    gld16(Bp + (size_t)(n0 + w*32 + j*16 + srow)*DMODEL + scol, &sB[0][w*32 + j*16][0]);
  }
  __syncthreads();

  int cur = 0;
  for(int k0=0;k0<DMODEL;k0+=32){
    if(k0 + 32 < DMODEL){
      #pragma unroll
      for(int j=0;j<2;j++){
        gld16(Ap + (size_t)(m0 + w*32 + j*16 + srow)*DMODEL + k0+32 + scol, &sA[cur^1][w*32 + j*16][0]);
        gld16(Bp + (size_t)(n0 + w*32 + j*16 + srow)*DMODEL + k0+32 + scol, &sB[cur^1][w*32 + j*16][0]);
      }
    }
    bf16x8 a[4], b[4];
    #pragma unroll
    for(int i=0;i<4;i++) a[i] = ld8(&sA[cur][wm + i*16 + lm][quad*8]);
    #pragma unroll
    for(int j=0;j<4;j++) b[j] = ld8(&sB[cur][wn + j*16 + lm][quad*8]);
    #pragma unroll
    for(int i=0;i<4;i++)
      #pragma unroll
      for(int j=0;j<4;j++)
        acc[i][j] = __builtin_amdgcn_mfma_f32_16x16x32_bf16(a[i], b[j], acc[i][j], 0, 0, 0);
    __syncthreads();       // drains this step's STAGE(next) vmcnt AFTER compute
    cur ^= 1;
  }

  if(z == 2){
    // C/D: row (A-side) = d-coord, col (B-side) = s-coord; bias indexed by row
    #pragma unroll
    for(int i=0;i<4;i++){
      #pragma unroll
      for(int r=0;r<4;r++){
        const int row = m0 + wm + i*16 + quad*4 + r;    // 0..1023: h,d
        const int h_ = row >> 6, d_ = row & 63;
        const float bb = bias[row];
        #pragma unroll
        for(int j=0;j<4;j++){
          const int c = n0 + wn + j*16 + lm;            // 0..4095: b,s (lm -> consecutive)
          const int b_ = c >> 11, s_ = c & 2047;
          vT_ws[((size_t)(b_*NHEAD + h_)*DKDIM + d_)*S_LEN + s_] = f2b(acc[i][j][r] + bb);
        }
      }
    }
  }else{
    #pragma unroll
    for(int j=0;j<4;j++){
      const int n  = n0 + wn + j*16 + lm;
      const float bb = bias[n] * scl;
      const int h_ = n >> 6, d_ = n & 63;
      #pragma unroll
      for(int i=0;i<4;i++){
        #pragma unroll
        for(int r=0;r<4;r++){
          const int m  = m0 + wm + i*16 + quad*4 + r;   // C/D: row = quad*4+reg
          const int b_ = m >> 11, s_ = m & 2047;
          const unsigned short o = f2b(fmaf(acc[i][j][r], scl, bb));
          if(z == 0) q_ws[((size_t)(b_*NHEAD + h_)*S_LEN + s_)*DKDIM + d_] = o;
          else       k_ws[((size_t)(b_*NHEAD + h_)*S_LEN + s_)*DKDIM + d_] = o;
        }
      }
    }
  }
}

// ---------------- flash attention v11 (byte-identical to R10's passing kernel) ----------
__global__ __launch_bounds__(128) void flash_attn(
    const unsigned short* __restrict__ q_ws,
    const unsigned short* __restrict__ k_ws,
    const unsigned short* __restrict__ vT_ws,
    unsigned short* __restrict__ attn_c)
{
  __shared__ __align__(16) unsigned short kt[2][64][64];   // [buf][j][k], chunk-swizzled
  __shared__ __align__(16) unsigned short vt[2][64][64];   // [buf][d][j], chunk-swizzled
  const int bh = blockIdx.x;
  const int b_ = bh >> 4, h_ = bh & 15;
  const int tid = threadIdx.x;
  const int w = tid >> 6, lane = tid & 63;
  const int l = lane & 31, hi = lane >> 5;
  const int r0 = blockIdx.y * 64 + w * 32;

  const unsigned short* qp = q_ws  + ((size_t)bh * S_LEN + r0) * DKDIM;
  const unsigned short* kp = k_ws  + (size_t)bh * S_LEN * DKDIM;
  const unsigned short* vp = vT_ws + (size_t)bh * DKDIM * S_LEN;

  bf16x8 qf[4];
  #pragma unroll
  for(int m=0;m<4;m++)
    qf[m] = ld8(qp + (size_t)l*DKDIM + m*16 + hi*8);

  f32x16 o_acc[2];
  #pragma unroll
  for(int i=0;i<16;i++){ o_acc[0][i] = 0.f; o_acc[1][i] = 0.f; }
  float rsum = 0.f;

  const int srow = (lane >> 3) & 7;          // row within 8-row group
  const int schk = (lane & 7) ^ srow;        // pre-swizzled global 16B-chunk index
  int kofs[4], vofs[4];                      // per-lane global offsets (shorts)
  #pragma unroll
  for(int p=0;p<4;p++){
    const int row = w*32 + p*8 + srow;       // row&7 == srow
    kofs[p] = row*DKDIM + schk*8;            // + t*4096 per tile
    vofs[p] = row*S_LEN + schk*8;            // + t*64 per tile
  }

  #pragma unroll
  for(int p=0;p<4;p++){
    gld16(kp + kofs[p], &kt[0][w*32 + p*8][0]);
    gld16(vp + vofs[p], &vt[0][w*32 + p*8][0]);
  }
  __syncthreads();

  for(int t=0;t<32;t++){
    const int buf = t & 1, nb = buf ^ 1;
    if(t < 31){
      #pragma unroll
      for(int p=0;p<4;p++){
        gld16(kp + (t+1)*4096 + kofs[p], &kt[nb][w*32 + p*8][0]);
        gld16(vp + (t+1)*64   + vofs[p], &vt[nb][w*32 + p*8][0]);
      }
    }

    // ---- QK^T for BOTH j-blocks ----
    f32x16 sacc0, sacc1;
    #pragma unroll
    for(int q=0;q<16;q++){ sacc0[q] = 0.f; sacc1[q] = 0.f; }
    __builtin_amdgcn_s_setprio(1);
    #pragma unroll
    for(int m=0;m<4;m++){
      bf16x8 kf0 = ld8(&kt[buf][     l][((2*m + hi) ^ (l & 7)) * 8]);
      bf16x8 kf1 = ld8(&kt[buf][32 + l][((2*m + hi) ^ (l & 7)) * 8]);
      sacc0 = __builtin_amdgcn_mfma_f32_32x32x16_bf16(kf0, qf[m], sacc0, 0, 0, 0);
      sacc1 = __builtin_amdgcn_mfma_f32_32x32x16_bf16(kf1, qf[m], sacc1, 0, 0, 0);
    }
    __builtin_amdgcn_s_setprio(0);

    // ---- softmax jb=0 ----
    unsigned int pk0[8];
    {
      float ea = 0.f;
      #pragma unroll
      for(int r2=0;r2<4;r2++){
        const float e0 = fexp2(sacc0[4*r2+0]);
        const float e1 = fexp2(sacc0[4*r2+1]);
        const float e2 = fexp2(sacc0[4*r2+2]);
        const float e3 = fexp2(sacc0[4*r2+3]);
        ea += (e0+e1)+(e2+e3);
        const unsigned int u0 = __float_as_uint(e0) + 0x8000u;
        const unsigned int u1 = __float_as_uint(e1) + 0x8000u;
        const unsigned int u2 = __float_as_uint(e2) + 0x8000u;
        const unsigned int u3 = __float_as_uint(e3) + 0x8000u;
        pk0[2*r2]   = __builtin_amdgcn_perm(u1, u0, 0x07060302u);
        pk0[2*r2+1] = __builtin_amdgcn_perm(u3, u2, 0x07060302u);
      }
      rsum += ea;
    }

    // ---- PV jb=0 ----
    __builtin_amdgcn_s_setprio(1);
    #pragma unroll
    for(int c=0;c<2;c++){
      unsigned int a0 = pk0[4*c],   b0 = pk0[4*c+2];
      unsigned int a1 = pk0[4*c+1], b1 = pk0[4*c+3];
      pl32swap(a0, b0);
      pl32swap(a1, b1);
      union { unsigned int u[4]; bf16x8 v; } pa;
      pa.u[0] = a0; pa.u[1] = a1; pa.u[2] = b0; pa.u[3] = b1;
      #pragma unroll
      for(int dblk=0;dblk<2;dblk++){
        bf16x8 vf = ld8(&vt[buf][dblk*32 + l][((2*c + hi) ^ (l & 7)) * 8]);
        o_acc[dblk] = __builtin_amdgcn_mfma_f32_32x32x16_bf16(pa.v, vf, o_acc[dblk], 0, 0, 0);
      }
    }
    __builtin_amdgcn_s_setprio(0);

    // ---- softmax jb=1 ----
    unsigned int pk1[8];
    {
      float ea = 0.f;
      #pragma unroll
      for(int r2=0;r2<4;r2++){
        const float e0 = fexp2(sacc1[4*r2+0]);
        const float e1 = fexp2(sacc1[4*r2+1]);
        const float e2 = fexp2(sacc1[4*r2+2]);
        const float e3 = fexp2(sacc1[4*r2+3]);
        ea += (e0+e1)+(e2+e3);
        const unsigned int u0 = __float_as_uint(e0) + 0x8000u;
        const unsigned int u1 = __float_as_uint(e1) + 0x8000u;
        const unsigned int u2 = __float_as_uint(e2) + 0x8000u;
        const unsigned int u3 = __float_as_uint(e3) + 0x8000u;
        pk1[2*r2]   = __builtin_amdgcn_perm(u1, u0, 0x07060302u);
        pk1[2*r2+1] = __builtin_amdgcn_perm(u3, u2, 0x07060302u);
      }
      rsum += ea;
    }

    // ---- PV jb=1 ----
    __builtin_amdgcn_s_setprio(1);
    #pragma unroll
    for(int c=0;c<2;c++){
      unsigned int a0 = pk1[4*c],   b0 = pk1[4*c+2];
      unsigned int a1 = pk1[4*c+1], b1 = pk1[4*c+3];
      pl32swap(a0, b0);
      pl32swap(a1, b1);
      union { unsigned int u[4]; bf16x8 v; } pa;
      pa.u[0] = a0; pa.u[1] = a1; pa.u[2] = b0; pa.u[3] = b1;
      #pragma unroll
      for(int dblk=0;dblk<2;dblk++){
        bf16x8 vf = ld8(&vt[buf][dblk*32 + l][((4 + 2*c + hi) ^ (l & 7)) * 8]);
        o_acc[dblk] = __builtin_amdgcn_mfma_f32_32x32x16_bf16(pa.v, vf, o_acc[dblk], 0, 0, 0);
      }
    }
    __builtin_amdgcn_s_setprio(0);

    __syncthreads();
  }

  rsum += __shfl_xor(rsum, 32);
  const float rinv_l = __frcp_rn(rsum);

  #pragma unroll
  for(int r=0;r<16;r++){
    const int qr = (r&3) + 8*(r>>2) + 4*hi;
    const float ri = __shfl(rinv_l, qr);
    const size_t ob = ((size_t)(b_*S_LEN + r0 + qr))*DMODEL + h_*DKDIM + l;
    attn_c[ob]      = f2b(o_acc[0][r] * ri);
    attn_c[ob + 32] = f2b(o_acc[1][r] * ri);
  }
}

// ---------------- output projection: 64x128 tiles (512 blocks = 2/CU), double-buffered ----
__global__ __launch_bounds__(256) void gemm_out(
    const unsigned short* __restrict__ A,
    const unsigned short* __restrict__ Wt,
    const float* __restrict__ bias,
    float* __restrict__ out)
{
  __shared__ __align__(16) unsigned short sA[2][64][32];
  __shared__ __align__(16) unsigned short sB[2][128][32];
  const int m0 = blockIdx.x * 64, n0 = blockIdx.y * 128;
  const int tid = threadIdx.x;
  const int w = tid >> 6, lane = tid & 63, quad = lane >> 4, lm = lane & 15;
  const int wm = (w & 1) * 32, wn = (w >> 1) * 64;
  const int srow = lane >> 2, scol = (lane & 3) * 8;

  f32x4 acc[2][4];
  #pragma unroll
  for(int i=0;i<2;i++)
    #pragma unroll
    for(int j=0;j<4;j++){ f32x4 z4 = {0.f,0.f,0.f,0.f}; acc[i][j] = z4; }

  // prologue: stage k0=0 into buf 0
  gld16(A + (size_t)(m0 + w*16 + srow)*DMODEL + scol, &sA[0][w*16][0]);
  #pragma unroll
  for(int j=0;j<2;j++)
    gld16(Wt + (size_t)(n0 + w*32 + j*16 + srow)*DMODEL + scol, &sB[0][w*32 + j*16][0]);
  __syncthreads();

  int cur = 0;
  for(int k0=0;k0<DMODEL;k0+=32){
    if(k0 + 32 < DMODEL){
      gld16(A + (size_t)(m0 + w*16 + srow)*DMODEL + k0+32 + scol, &sA[cur^1][w*16][0]);
      #pragma unroll
      for(int j=0;j<2;j++)
        gld16(Wt + (size_t)(n0 + w*32 + j*16 + srow)*DMODEL + k0+32 + scol, &sB[cur^1][w*32 + j*16][0]);
    }
    bf16x8 a[2], b[4];
    #pragma unroll
    for(int i=0;i<2;i++) a[i] = ld8(&sA[cur][wm + i*16 + lm][quad*8]);
    #pragma unroll
    for(int j=0;j<4;j++) b[j] = ld8(&sB[cur][wn + j*16 + lm][quad*8]);
    #pragma unroll
    for(int i=0;i<2;i++)
      #pragma unroll
      for(int j=0;j<4;j++)
        acc[i][j] = __builtin_amdgcn_mfma_f32_16x16x32_bf16(a[i], b[j], acc[i][j], 0, 0, 0);
    __syncthreads();
    cur ^= 1;
  }

  #pragma unroll
  for(int j=0;j<4;j++){
    const int n = n0 + wn + j*16 + lm;
    const float bb = bias[n];
    #pragma unroll
    for(int i=0;i<2;i++){
      #pragma unroll
      for(int r=0;r<4;r++){
        const int m = m0 + wm + i*16 + quad*4 + r;
        out[(size_t)m*DMODEL + n] = acc[i][j][r] + bb;
      }
    }
  }
}

extern "C" void kernel_launch(void* const* d_in, const int* in_sizes, int n_in,
                              void* d_out, int out_size, void* d_ws, size_t ws_size,
                              hipStream_t stream)
{
  const float* X  = (const float*)d_in[0];
  const float* Wq = (const float*)d_in[1];
  const float* bq = (const float*)d_in[2];
  const float* Wk = (const float*)d_in[3];
  const float* bk = (const float*)d_in[4];
  const float* Wv = (const float*)d_in[5];
  const float* bv = (const float*)d_in[6];
  const float* Wo = (const float*)d_in[7];
  const float* bo = (const float*)d_in[8];

  unsigned short* ws = (unsigned short*)d_ws;
  const size_t WMAT = (size_t)DMODEL * DMODEL;                 // 1M elems
  const size_t QKV  = (size_t)NBATCH * NHEAD * S_LEN * DKDIM;  // 4M elems
  unsigned short* Wt     = ws;               // 4 transposed bf16 weights (4M elems)
  unsigned short* Xc     = ws + 4*WMAT;      // bf16 X (4M elems)
  unsigned short* q_ws   = Xc + QKV;
  unsigned short* k_ws   = q_ws + QKV;
  unsigned short* vT_ws  = k_ws + QKV;
  unsigned short* attn_c = Xc;               // alias: Xc dead after gemm_qkv
  float* out = (float*)d_out;

  convert_x  <<<dim3(2048),     256, 0, stream>>>(X, Xc);
  transpose_w<<<dim3(16,16,4),  256, 0, stream>>>(Wq, Wk, Wv, Wo, Wt);
  gemm_qkv   <<<dim3(32,8,3),   256, 0, stream>>>(Xc, Wt, bq, bk, bv, q_ws, k_ws, vT_ws);
  flash_attn <<<dim3(32,32),    128, 0, stream>>>(q_ws, k_ws, vT_ws, attn_c);
  gemm_out   <<<dim3(64,8),     256, 0, stream>>>(attn_c, Wt + 3*WMAT, bo, out);
}